// Round 1
// baseline (1652.698 us; speedup 1.0000x reference)
//
#include <hip/hip_runtime.h>
#include <hip/hip_bf16.h>
#include <math.h>

#define NF 50000
#define NM 5000
#define EFF 800000
#define EMF 200000

__device__ __forceinline__ unsigned mono(float f) {
    unsigned u = __float_as_uint(f);
    return (u & 0x80000000u) ? ~u : (u | 0x80000000u);
}
__device__ __forceinline__ float demono(unsigned m) {
    unsigned u = (m & 0x80000000u) ? (m & 0x7FFFFFFFu) : ~m;
    return __uint_as_float(u);
}

// ---- Phase A: timestep embedding + FiLM (tiny) ----
__global__ void k_small(const float* __restrict__ tau,
                        const float* __restrict__ tcW1, const float* __restrict__ tcb1,
                        const float* __restrict__ tcW2, const float* __restrict__ tcb2,
                        float* __restrict__ misc) {
    __shared__ float temb[16], h[16];
    int tid = threadIdx.x;
    float t = tau[0];
    if (tid < 8) {
        float fr = expf(-logf(10000.0f) * (float)tid / 8.0f);
        float a = t * fr;
        temb[tid] = sinf(a);
        temb[tid + 8] = cosf(a);
    }
    __syncthreads();
    if (tid < 16) {
        float acc = tcb1[tid];
#pragma unroll
        for (int i = 0; i < 16; i++) acc += temb[i] * tcW1[i * 16 + tid];
        h[tid] = fmaxf(acc, 0.f);
        misc[tid] = temb[tid];
    }
    __syncthreads();
    if (tid < 32) {
        float acc = tcb2[tid];
#pragma unroll
        for (int i = 0; i < 16; i++) acc += h[i] * tcW2[i * 32 + tid];
        misc[16 + tid] = acc;   // misc[16..31]=scale, misc[32..47]=shift
    }
}

// ---- Phase B: membrane encoder + membrane decoder ----
__global__ void k_memb(const float* __restrict__ y,
                       const float* __restrict__ W1, const float* __restrict__ b1,
                       const float* __restrict__ W2, const float* __restrict__ b2,
                       const float* __restrict__ decW, const float* __restrict__ decb,
                       const float* __restrict__ misc,
                       float* __restrict__ xm_out, float* __restrict__ outm) {
    __shared__ float sW1[304], sb1[16], sW2[256], sb2[16], sD[48], sdb[3], st[16];
    int tid = threadIdx.x;
    for (int i = tid; i < 304; i += 256) sW1[i] = W1[i];
    for (int i = tid; i < 256; i += 256) sW2[i] = W2[i];
    if (tid < 16) { sb1[tid] = b1[tid]; sb2[tid] = b2[tid]; st[tid] = misc[tid]; }
    if (tid < 48) sD[tid] = decW[tid];
    if (tid < 3) sdb[tid] = decb[tid];
    __syncthreads();
    int n = blockIdx.x * 256 + tid;
    if (n >= NM) return;
    float i0 = y[n * 3], i1 = y[n * 3 + 1], i2 = y[n * 3 + 2];
    float h1[16];
#pragma unroll
    for (int c = 0; c < 16; c++) {
        float acc = sb1[c] + i0 * sW1[c] + i1 * sW1[16 + c] + i2 * sW1[32 + c];
#pragma unroll
        for (int i = 0; i < 16; i++) acc += st[i] * sW1[(3 + i) * 16 + c];
        h1[c] = fmaxf(acc, 0.f);
    }
    float xm[16];
#pragma unroll
    for (int c = 0; c < 16; c++) {
        float acc = sb2[c];
#pragma unroll
        for (int i = 0; i < 16; i++) acc += h1[i] * sW2[i * 16 + c];
        xm[c] = fmaxf(acc, 0.f);
    }
#pragma unroll
    for (int q = 0; q < 4; q++) {
        float4 v = make_float4(xm[4 * q], xm[4 * q + 1], xm[4 * q + 2], xm[4 * q + 3]);
        reinterpret_cast<float4*>(xm_out)[n * 4 + q] = v;
    }
#pragma unroll
    for (int k = 0; k < 3; k++) {
        float acc = sdb[k];
#pragma unroll
        for (int i = 0; i < 16; i++) acc += xm[i] * sD[i * 3 + k];
        outm[n * 3 + k] = acc;
    }
}

// ---- Phase C: flow encoder + root transform ----
__global__ void k_flow0(const float* __restrict__ x,
                        const float* __restrict__ W, const float* __restrict__ b,
                        const float* __restrict__ Wr, const float* __restrict__ br,
                        const float* __restrict__ misc,
                        float* __restrict__ xf0, float* __restrict__ root) {
    __shared__ float sW[304], sb[16], sWr[256], sbr[16], st[16];
    int tid = threadIdx.x;
    for (int i = tid; i < 304; i += 256) sW[i] = W[i];
    for (int i = tid; i < 256; i += 256) sWr[i] = Wr[i];
    if (tid < 16) { sb[tid] = b[tid]; sbr[tid] = br[tid]; st[tid] = misc[tid]; }
    __syncthreads();
    int n = blockIdx.x * 256 + tid;
    if (n >= NF) return;
    float i0 = x[n * 3], i1 = x[n * 3 + 1], i2 = x[n * 3 + 2];
    float f[16];
#pragma unroll
    for (int c = 0; c < 16; c++) {
        float acc = sb[c] + i0 * sW[c] + i1 * sW[16 + c] + i2 * sW[32 + c];
#pragma unroll
        for (int i = 0; i < 16; i++) acc += st[i] * sW[(3 + i) * 16 + c];
        f[c] = acc;
    }
#pragma unroll
    for (int q = 0; q < 4; q++) {
        float4 v = make_float4(f[4 * q], f[4 * q + 1], f[4 * q + 2], f[4 * q + 3]);
        reinterpret_cast<float4*>(xf0)[n * 4 + q] = v;
    }
    float r[16];
#pragma unroll
    for (int c = 0; c < 16; c++) {
        float acc = sbr[c];
#pragma unroll
        for (int i = 0; i < 16; i++) acc += f[i] * sWr[i * 16 + c];
        r[c] = acc;
    }
#pragma unroll
    for (int q = 0; q < 4; q++) {
        float4 v = make_float4(r[4 * q], r[4 * q + 1], r[4 * q + 2], r[4 * q + 3]);
        reinterpret_cast<float4*>(root)[n * 4 + q] = v;
    }
}

// ---- Phase D1: attention scores + segment max ----
__global__ void k_attn1(const float* __restrict__ xf0, const float* __restrict__ xm,
                        const float* __restrict__ ea,
                        const int* __restrict__ src, const int* __restrict__ dst,
                        const float* __restrict__ Wq, const float* __restrict__ Wk,
                        const float* __restrict__ We,
                        float* __restrict__ score, unsigned* __restrict__ smax) {
    __shared__ float sq[256], sk[256], se[96];
    int tid = threadIdx.x;
    for (int i = tid; i < 256; i += 256) { sq[i] = Wq[i]; sk[i] = Wk[i]; }
    if (tid < 96) se[tid] = We[tid];
    __syncthreads();
    int t = blockIdx.x * 256 + tid;
    if (t >= EMF) return;
    int s = src[t], d = dst[t];
    float xq[16], xs[16];
#pragma unroll
    for (int q = 0; q < 4; q++) {
        float4 v = reinterpret_cast<const float4*>(xf0)[d * 4 + q];
        xq[4 * q] = v.x; xq[4 * q + 1] = v.y; xq[4 * q + 2] = v.z; xq[4 * q + 3] = v.w;
        float4 w = reinterpret_cast<const float4*>(xm)[s * 4 + q];
        xs[4 * q] = w.x; xs[4 * q + 1] = w.y; xs[4 * q + 2] = w.z; xs[4 * q + 3] = w.w;
    }
    float e0 = ea[t * 6], e1 = ea[t * 6 + 1], e2 = ea[t * 6 + 2],
          e3 = ea[t * 6 + 3], e4 = ea[t * 6 + 4], e5 = ea[t * 6 + 5];
    float sc = 0.f;
#pragma unroll
    for (int j = 0; j < 16; j++) {
        float qj = 0.f;
        float kj = e0 * se[j] + e1 * se[16 + j] + e2 * se[32 + j]
                 + e3 * se[48 + j] + e4 * se[64 + j] + e5 * se[80 + j];
#pragma unroll
        for (int i = 0; i < 16; i++) {
            qj += xq[i] * sq[i * 16 + j];
            kj += xs[i] * sk[i * 16 + j];
        }
        sc += qj * kj;
    }
    sc *= 0.25f;
    score[t] = sc;
    atomicMax(&smax[d], mono(sc));
}

// ---- Phase D2: exp + unnormalized numer/den scatter ----
__global__ void k_attn2(const float* __restrict__ xm,
                        const int* __restrict__ src, const int* __restrict__ dst,
                        const float* __restrict__ score, const unsigned* __restrict__ smax,
                        const float* __restrict__ Wv,
                        float* __restrict__ den, float* __restrict__ num) {
    __shared__ float sv[256];
    int tid = threadIdx.x;
    for (int i = tid; i < 256; i += 256) sv[i] = Wv[i];
    __syncthreads();
    int t = blockIdx.x * 256 + tid;
    if (t >= EMF) return;
    int s = src[t], d = dst[t];
    float e = expf(score[t] - demono(smax[d]));
    atomicAdd(&den[d], e);
    float xs[16];
#pragma unroll
    for (int q = 0; q < 4; q++) {
        float4 w = reinterpret_cast<const float4*>(xm)[s * 4 + q];
        xs[4 * q] = w.x; xs[4 * q + 1] = w.y; xs[4 * q + 2] = w.z; xs[4 * q + 3] = w.w;
    }
#pragma unroll
    for (int j = 0; j < 16; j++) {
        float vj = 0.f;
#pragma unroll
        for (int i = 0; i < 16; i++) vj += xs[i] * sv[i * 16 + j];
        atomicAdd(&num[d * 16 + j], e * vj);
    }
}

// ---- Phase E: fused NNConv edge kernel (the big one) ----
__global__ void __launch_bounds__(512, 2) k_edge(
        const float* __restrict__ ea, const int* __restrict__ src, const int* __restrict__ dst,
        const float* __restrict__ K0, const float* __restrict__ kb0,
        const float* __restrict__ K1, const float* __restrict__ kb1,
        const float* __restrict__ K2, const float* __restrict__ kb2,
        const float* __restrict__ xf0,
        float* __restrict__ agg, float* __restrict__ deg) {
    __shared__ __align__(16) float sK0[384];
    __shared__ float skb0[64];
    __shared__ __align__(16) float sK1T[4096];   // [c][d] transposed
    __shared__ float skb1[64];
    __shared__ __align__(16) float sK2[16384];   // [c][256]
    __shared__ __align__(16) float skb2[256];
    int tid = threadIdx.x;
    for (int i = tid; i < 384; i += 512) sK0[i] = K0[i];
    if (tid < 64) { skb0[tid] = kb0[tid]; skb1[tid] = kb1[tid]; }
    for (int i = tid; i < 4096; i += 512) sK1T[(i & 63) * 64 + (i >> 6)] = K1[i];
    for (int i = tid; i < 16384; i += 512) sK2[i] = K2[i];
    if (tid < 256) skb2[tid] = kb2[tid];
    __syncthreads();
    int t = blockIdx.x * 512 + tid;
    if (t >= EFF) return;
    int s = src[t], d = dst[t];
    float e0 = ea[t * 6], e1 = ea[t * 6 + 1], e2 = ea[t * 6 + 2],
          e3 = ea[t * 6 + 3], e4 = ea[t * 6 + 4], e5 = ea[t * 6 + 5];
    float x[16];
#pragma unroll
    for (int q = 0; q < 4; q++) {
        float4 v = reinterpret_cast<const float4*>(xf0)[s * 4 + q];
        x[4 * q] = v.x; x[4 * q + 1] = v.y; x[4 * q + 2] = v.z; x[4 * q + 3] = v.w;
    }
    float kh0[64];
#pragma unroll
    for (int dd = 0; dd < 64; dd++) {
        float a = skb0[dd] + e0 * sK0[dd] + e1 * sK0[64 + dd] + e2 * sK0[128 + dd]
                + e3 * sK0[192 + dd] + e4 * sK0[256 + dd] + e5 * sK0[320 + dd];
        kh0[dd] = fmaxf(a, 0.f);
    }
    float msg[16];
#pragma unroll
    for (int i = 0; i < 16; i++) {          // kb2 bias term: kb2mat @ x
        float a = 0.f;
#pragma unroll
        for (int j = 0; j < 16; j++) a += skb2[i * 16 + j] * x[j];
        msg[i] = a;
    }
    const float4* sK1T4 = reinterpret_cast<const float4*>(sK1T);
    const float4* sK24  = reinterpret_cast<const float4*>(sK2);
#pragma unroll 1
    for (int c = 0; c < 64; c++) {
        float a = skb1[c];
#pragma unroll
        for (int d4 = 0; d4 < 16; d4++) {
            float4 v = sK1T4[c * 16 + d4];
            a += v.x * kh0[4 * d4] + v.y * kh0[4 * d4 + 1]
               + v.z * kh0[4 * d4 + 2] + v.w * kh0[4 * d4 + 3];
        }
        float kh1c = fmaxf(a, 0.f);
#pragma unroll
        for (int i = 0; i < 16; i++) {
            float4 v0 = sK24[c * 64 + i * 4 + 0];
            float4 v1 = sK24[c * 64 + i * 4 + 1];
            float4 v2 = sK24[c * 64 + i * 4 + 2];
            float4 v3 = sK24[c * 64 + i * 4 + 3];
            float zi = v0.x * x[0] + v0.y * x[1] + v0.z * x[2] + v0.w * x[3]
                     + v1.x * x[4] + v1.y * x[5] + v1.z * x[6] + v1.w * x[7]
                     + v2.x * x[8] + v2.y * x[9] + v2.z * x[10] + v2.w * x[11]
                     + v3.x * x[12] + v3.y * x[13] + v3.z * x[14] + v3.w * x[15];
            msg[i] += kh1c * zi;
        }
    }
#pragma unroll
    for (int i = 0; i < 16; i++) atomicAdd(&agg[d * 16 + i], msg[i]);
    atomicAdd(&deg[d], 1.0f);
}

// ---- Phase F: combine + FiLM + flow decoder ----
__global__ void k_final(const float* __restrict__ root, const float* __restrict__ agg,
                        const float* __restrict__ num, const float* __restrict__ den,
                        const float* __restrict__ deg, const float* __restrict__ misc,
                        const float* __restrict__ dW, const float* __restrict__ db,
                        float* __restrict__ out) {
    __shared__ float ssc[16], ssh[16], sD[48], sdb[3];
    int tid = threadIdx.x;
    if (tid < 16) { ssc[tid] = misc[16 + tid]; ssh[tid] = misc[32 + tid]; }
    if (tid < 48) sD[tid] = dW[tid];
    if (tid < 3) sdb[tid] = db[tid];
    __syncthreads();
    int n = blockIdx.x * 256 + tid;
    if (n >= NF) return;
    float rdg = 1.0f / fmaxf(deg[n], 1.0f);
    float rdn = 1.0f / (den[n] + 1e-16f);
    float xo[16];
#pragma unroll
    for (int q = 0; q < 4; q++) {
        float4 r4 = reinterpret_cast<const float4*>(root)[n * 4 + q];
        float4 a4 = reinterpret_cast<const float4*>(agg)[n * 4 + q];
        float4 m4 = reinterpret_cast<const float4*>(num)[n * 4 + q];
        float v0 = r4.x + a4.x * rdg + m4.x * rdn;
        float v1 = r4.y + a4.y * rdg + m4.y * rdn;
        float v2 = r4.z + a4.z * rdg + m4.z * rdn;
        float v3 = r4.w + a4.w * rdg + m4.w * rdn;
        float r;
        r = fmaxf(v0, 0.f); xo[4 * q + 0] = r + (r * ssc[4 * q + 0] + ssh[4 * q + 0]);
        r = fmaxf(v1, 0.f); xo[4 * q + 1] = r + (r * ssc[4 * q + 1] + ssh[4 * q + 1]);
        r = fmaxf(v2, 0.f); xo[4 * q + 2] = r + (r * ssc[4 * q + 2] + ssh[4 * q + 2]);
        r = fmaxf(v3, 0.f); xo[4 * q + 3] = r + (r * ssc[4 * q + 3] + ssh[4 * q + 3]);
    }
#pragma unroll
    for (int k = 0; k < 3; k++) {
        float acc = sdb[k];
#pragma unroll
        for (int i = 0; i < 16; i++) acc += xo[i] * sD[i * 3 + k];
        out[n * 3 + k] = acc;
    }
}

extern "C" void kernel_launch(void* const* d_in, const int* in_sizes, int n_in,
                              void* d_out, int out_size, void* d_ws, size_t ws_size,
                              hipStream_t stream) {
    const float* flow_x   = (const float*)d_in[0];
    const float* memb_y   = (const float*)d_in[1];
    const float* tau      = (const float*)d_in[2];
    const float* ea_ff    = (const float*)d_in[3];
    const float* ea_mf    = (const float*)d_in[4];
    const float* enc_f_W  = (const float*)d_in[5];
    const float* enc_f_b  = (const float*)d_in[6];
    const float* enc_m_W1 = (const float*)d_in[7];
    const float* enc_m_b1 = (const float*)d_in[8];
    const float* enc_m_W2 = (const float*)d_in[9];
    const float* enc_m_b2 = (const float*)d_in[10];
    const float* K0       = (const float*)d_in[11];
    const float* kb0      = (const float*)d_in[12];
    const float* K1       = (const float*)d_in[13];
    const float* kb1      = (const float*)d_in[14];
    const float* K2       = (const float*)d_in[15];
    const float* kb2      = (const float*)d_in[16];
    const float* W_root   = (const float*)d_in[17];
    const float* b_root   = (const float*)d_in[18];
    const float* Wq       = (const float*)d_in[19];
    const float* Wk       = (const float*)d_in[20];
    const float* We       = (const float*)d_in[21];
    const float* Wv       = (const float*)d_in[22];
    const float* tc_W1    = (const float*)d_in[23];
    const float* tc_b1    = (const float*)d_in[24];
    const float* tc_W2    = (const float*)d_in[25];
    const float* tc_b2    = (const float*)d_in[26];
    const float* dec_f_W  = (const float*)d_in[27];
    const float* dec_f_b  = (const float*)d_in[28];
    const float* dec_m_W  = (const float*)d_in[29];
    const float* dec_m_b  = (const float*)d_in[30];
    const int* src_ff = (const int*)d_in[31];
    const int* dst_ff = (const int*)d_in[32];
    const int* src_mf = (const int*)d_in[33];
    const int* dst_mf = (const int*)d_in[34];

    float* out = (float*)d_out;
    float* ws = (float*)d_ws;
    // workspace layout (floats)
    float* misc = ws;                       // 64
    float* deg  = ws + 64;                  // NF   (zeroed)
    float* den  = deg + NF;                 // NF   (zeroed)
    unsigned* smax = (unsigned*)(den + NF); // NF   (zeroed; 0 < mono(any score))
    float* agg  = (float*)(smax + NF);      // NF*16 (zeroed)
    float* num  = agg + (size_t)NF * 16;    // NF*16 (zeroed)
    float* xm   = num + (size_t)NF * 16;    // NM*16
    float* xf0  = xm + (size_t)NM * 16;     // NF*16
    float* root = xf0 + (size_t)NF * 16;    // NF*16
    float* score = root + (size_t)NF * 16;  // EMF

    hipMemsetAsync(deg, 0, (size_t)NF * 35 * sizeof(float), stream);

    k_small<<<1, 64, 0, stream>>>(tau, tc_W1, tc_b1, tc_W2, tc_b2, misc);
    k_memb<<<(NM + 255) / 256, 256, 0, stream>>>(memb_y, enc_m_W1, enc_m_b1, enc_m_W2,
                                                 enc_m_b2, dec_m_W, dec_m_b, misc,
                                                 xm, out + (size_t)NF * 3);
    k_flow0<<<(NF + 255) / 256, 256, 0, stream>>>(flow_x, enc_f_W, enc_f_b, W_root, b_root,
                                                  misc, xf0, root);
    k_attn1<<<(EMF + 255) / 256, 256, 0, stream>>>(xf0, xm, ea_mf, src_mf, dst_mf,
                                                   Wq, Wk, We, score, smax);
    k_attn2<<<(EMF + 255) / 256, 256, 0, stream>>>(xm, src_mf, dst_mf, score, smax,
                                                   Wv, den, num);
    k_edge<<<(EFF + 511) / 512, 512, 0, stream>>>(ea_ff, src_ff, dst_ff, K0, kb0,
                                                  K1, kb1, K2, kb2, xf0, agg, deg);
    k_final<<<(NF + 255) / 256, 256, 0, stream>>>(root, agg, num, den, deg, misc,
                                                  dec_f_W, dec_f_b, out);
}

// Round 2
// 856.641 us; speedup vs baseline: 1.9293x; 1.9293x over previous
//
#include <hip/hip_runtime.h>
#include <hip/hip_bf16.h>
#include <math.h>

#define NF 50000
#define NM 5000
#define EFF 800000
#define EMF 200000

typedef __attribute__((ext_vector_type(8))) short s8;
typedef __attribute__((ext_vector_type(4))) float f4;

__device__ __forceinline__ unsigned mono(float f) {
    unsigned u = __float_as_uint(f);
    return (u & 0x80000000u) ? ~u : (u | 0x80000000u);
}
__device__ __forceinline__ float demono(unsigned m) {
    unsigned u = (m & 0x80000000u) ? (m & 0x7FFFFFFFu) : ~m;
    return __uint_as_float(u);
}
__device__ __forceinline__ short f2b(float f) {
    __hip_bfloat16 h = __float2bfloat16(f);
    return *reinterpret_cast<short*>(&h);
}

// ---- Phase A: timestep embedding + FiLM (tiny) ----
__global__ void k_small(const float* __restrict__ tau,
                        const float* __restrict__ tcW1, const float* __restrict__ tcb1,
                        const float* __restrict__ tcW2, const float* __restrict__ tcb2,
                        float* __restrict__ misc) {
    __shared__ float temb[16], h[16];
    int tid = threadIdx.x;
    float t = tau[0];
    if (tid < 8) {
        float fr = expf(-logf(10000.0f) * (float)tid / 8.0f);
        float a = t * fr;
        temb[tid] = sinf(a);
        temb[tid + 8] = cosf(a);
    }
    __syncthreads();
    if (tid < 16) {
        float acc = tcb1[tid];
#pragma unroll
        for (int i = 0; i < 16; i++) acc += temb[i] * tcW1[i * 16 + tid];
        h[tid] = fmaxf(acc, 0.f);
        misc[tid] = temb[tid];
    }
    __syncthreads();
    if (tid < 32) {
        float acc = tcb2[tid];
#pragma unroll
        for (int i = 0; i < 16; i++) acc += h[i] * tcW2[i * 32 + tid];
        misc[16 + tid] = acc;   // misc[16..31]=scale, misc[32..47]=shift
    }
}

// ---- Phase B: membrane encoder + membrane decoder ----
__global__ void k_memb(const float* __restrict__ y,
                       const float* __restrict__ W1, const float* __restrict__ b1,
                       const float* __restrict__ W2, const float* __restrict__ b2,
                       const float* __restrict__ decW, const float* __restrict__ decb,
                       const float* __restrict__ misc,
                       float* __restrict__ xm_out, float* __restrict__ outm) {
    __shared__ float sW1[304], sb1[16], sW2[256], sb2[16], sD[48], sdb[3], st[16];
    int tid = threadIdx.x;
    for (int i = tid; i < 304; i += 256) sW1[i] = W1[i];
    for (int i = tid; i < 256; i += 256) sW2[i] = W2[i];
    if (tid < 16) { sb1[tid] = b1[tid]; sb2[tid] = b2[tid]; st[tid] = misc[tid]; }
    if (tid < 48) sD[tid] = decW[tid];
    if (tid < 3) sdb[tid] = decb[tid];
    __syncthreads();
    int n = blockIdx.x * 256 + tid;
    if (n >= NM) return;
    float i0 = y[n * 3], i1 = y[n * 3 + 1], i2 = y[n * 3 + 2];
    float h1[16];
#pragma unroll
    for (int c = 0; c < 16; c++) {
        float acc = sb1[c] + i0 * sW1[c] + i1 * sW1[16 + c] + i2 * sW1[32 + c];
#pragma unroll
        for (int i = 0; i < 16; i++) acc += st[i] * sW1[(3 + i) * 16 + c];
        h1[c] = fmaxf(acc, 0.f);
    }
    float xm[16];
#pragma unroll
    for (int c = 0; c < 16; c++) {
        float acc = sb2[c];
#pragma unroll
        for (int i = 0; i < 16; i++) acc += h1[i] * sW2[i * 16 + c];
        xm[c] = fmaxf(acc, 0.f);
    }
#pragma unroll
    for (int q = 0; q < 4; q++) {
        float4 v = make_float4(xm[4 * q], xm[4 * q + 1], xm[4 * q + 2], xm[4 * q + 3]);
        reinterpret_cast<float4*>(xm_out)[n * 4 + q] = v;
    }
#pragma unroll
    for (int k = 0; k < 3; k++) {
        float acc = sdb[k];
#pragma unroll
        for (int i = 0; i < 16; i++) acc += xm[i] * sD[i * 3 + k];
        outm[n * 3 + k] = acc;
    }
}

// ---- Phase C: flow encoder + root transform ----
__global__ void k_flow0(const float* __restrict__ x,
                        const float* __restrict__ W, const float* __restrict__ b,
                        const float* __restrict__ Wr, const float* __restrict__ br,
                        const float* __restrict__ misc,
                        float* __restrict__ xf0, float* __restrict__ root) {
    __shared__ float sW[304], sb[16], sWr[256], sbr[16], st[16];
    int tid = threadIdx.x;
    for (int i = tid; i < 304; i += 256) sW[i] = W[i];
    for (int i = tid; i < 256; i += 256) sWr[i] = Wr[i];
    if (tid < 16) { sb[tid] = b[tid]; sbr[tid] = br[tid]; st[tid] = misc[tid]; }
    __syncthreads();
    int n = blockIdx.x * 256 + tid;
    if (n >= NF) return;
    float i0 = x[n * 3], i1 = x[n * 3 + 1], i2 = x[n * 3 + 2];
    float f[16];
#pragma unroll
    for (int c = 0; c < 16; c++) {
        float acc = sb[c] + i0 * sW[c] + i1 * sW[16 + c] + i2 * sW[32 + c];
#pragma unroll
        for (int i = 0; i < 16; i++) acc += st[i] * sW[(3 + i) * 16 + c];
        f[c] = acc;
    }
#pragma unroll
    for (int q = 0; q < 4; q++) {
        float4 v = make_float4(f[4 * q], f[4 * q + 1], f[4 * q + 2], f[4 * q + 3]);
        reinterpret_cast<float4*>(xf0)[n * 4 + q] = v;
    }
    float r[16];
#pragma unroll
    for (int c = 0; c < 16; c++) {
        float acc = sbr[c];
#pragma unroll
        for (int i = 0; i < 16; i++) acc += f[i] * sWr[i * 16 + c];
        r[c] = acc;
    }
#pragma unroll
    for (int q = 0; q < 4; q++) {
        float4 v = make_float4(r[4 * q], r[4 * q + 1], r[4 * q + 2], r[4 * q + 3]);
        reinterpret_cast<float4*>(root)[n * 4 + q] = v;
    }
}

// ---- Phase D1: attention scores + segment max ----
__global__ void k_attn1(const float* __restrict__ xf0, const float* __restrict__ xm,
                        const float* __restrict__ ea,
                        const int* __restrict__ src, const int* __restrict__ dst,
                        const float* __restrict__ Wq, const float* __restrict__ Wk,
                        const float* __restrict__ We,
                        float* __restrict__ score, unsigned* __restrict__ smax) {
    __shared__ float sq[256], sk[256], se[96];
    int tid = threadIdx.x;
    for (int i = tid; i < 256; i += 256) { sq[i] = Wq[i]; sk[i] = Wk[i]; }
    if (tid < 96) se[tid] = We[tid];
    __syncthreads();
    int t = blockIdx.x * 256 + tid;
    if (t >= EMF) return;
    int s = src[t], d = dst[t];
    float xq[16], xs[16];
#pragma unroll
    for (int q = 0; q < 4; q++) {
        float4 v = reinterpret_cast<const float4*>(xf0)[d * 4 + q];
        xq[4 * q] = v.x; xq[4 * q + 1] = v.y; xq[4 * q + 2] = v.z; xq[4 * q + 3] = v.w;
        float4 w = reinterpret_cast<const float4*>(xm)[s * 4 + q];
        xs[4 * q] = w.x; xs[4 * q + 1] = w.y; xs[4 * q + 2] = w.z; xs[4 * q + 3] = w.w;
    }
    float e0 = ea[t * 6], e1 = ea[t * 6 + 1], e2 = ea[t * 6 + 2],
          e3 = ea[t * 6 + 3], e4 = ea[t * 6 + 4], e5 = ea[t * 6 + 5];
    float sc = 0.f;
#pragma unroll
    for (int j = 0; j < 16; j++) {
        float qj = 0.f;
        float kj = e0 * se[j] + e1 * se[16 + j] + e2 * se[32 + j]
                 + e3 * se[48 + j] + e4 * se[64 + j] + e5 * se[80 + j];
#pragma unroll
        for (int i = 0; i < 16; i++) {
            qj += xq[i] * sq[i * 16 + j];
            kj += xs[i] * sk[i * 16 + j];
        }
        sc += qj * kj;
    }
    sc *= 0.25f;
    score[t] = sc;
    atomicMax(&smax[d], mono(sc));
}

// ---- Phase D2: exp + unnormalized numer/den scatter ----
__global__ void k_attn2(const float* __restrict__ xm,
                        const int* __restrict__ src, const int* __restrict__ dst,
                        const float* __restrict__ score, const unsigned* __restrict__ smax,
                        const float* __restrict__ Wv,
                        float* __restrict__ den, float* __restrict__ num) {
    __shared__ float sv[256];
    int tid = threadIdx.x;
    for (int i = tid; i < 256; i += 256) sv[i] = Wv[i];
    __syncthreads();
    int t = blockIdx.x * 256 + tid;
    if (t >= EMF) return;
    int s = src[t], d = dst[t];
    float e = expf(score[t] - demono(smax[d]));
    atomicAdd(&den[d], e);
    float xs[16];
#pragma unroll
    for (int q = 0; q < 4; q++) {
        float4 w = reinterpret_cast<const float4*>(xm)[s * 4 + q];
        xs[4 * q] = w.x; xs[4 * q + 1] = w.y; xs[4 * q + 2] = w.z; xs[4 * q + 3] = w.w;
    }
#pragma unroll
    for (int j = 0; j < 16; j++) {
        float vj = 0.f;
#pragma unroll
        for (int i = 0; i < 16; i++) vj += xs[i] * sv[i * 16 + j];
        atomicAdd(&num[d * 16 + j], e * vj);
    }
}

// ---- Phase E: fused NNConv edge kernel, MFMA version ----
// Per wave: 16 edges. kh0 built directly in A-frag layout (lane: row=l&15,
// k=8*(l>>4)+jj per 32-K step). kh1 = mfma(kh0, K1). kh1 -> wave-private LDS
// (XOR swizzle ^((row&7)<<4)) -> re-read as B-frags. ker-tiles computed
// TRANSPOSED: C2[j,e] = mfma(K2T-frag(A), kh1-frag(B), b2) so the x-contraction
// is lane-local. No barriers in the main loop.
__global__ void __launch_bounds__(256, 2) k_edge_mfma(
        const float* __restrict__ ea, const int* __restrict__ src, const int* __restrict__ dst,
        const float* __restrict__ K0, const float* __restrict__ kb0,
        const float* __restrict__ K1, const float* __restrict__ kb1,
        const float* __restrict__ K2, const float* __restrict__ kb2,
        const float* __restrict__ xf0,
        float* __restrict__ agg, float* __restrict__ deg) {
    __shared__ __align__(16) char smem_big[32768];   // sK1 fp32 (16KB) then fragK2 bf16 (32KB)
    __shared__ __align__(16) float sK0[384];
    __shared__ __align__(16) float skb0[64];
    __shared__ __align__(16) float sb2[256];
    __shared__ __align__(16) short kh1buf[4][1024];  // per-wave [16 e][64 c] bf16, swizzled
    __shared__ __align__(16) float msgbuf[4][256];   // per-wave [16 e][16 i]

    const int tid = threadIdx.x;
    const int w = tid >> 6, lane = tid & 63;
    const int cl = lane & 15, g = lane >> 4;

    float* sK1 = (float*)smem_big;
    short* fragK2 = (short*)smem_big;
    for (int i = tid; i < 4096; i += 256) sK1[i] = K1[i];
    for (int i = tid; i < 384; i += 256) sK0[i] = K0[i];
    if (tid < 64) skb0[tid] = kb0[tid];
    if (tid < 256) sb2[tid] = kb2[tid];
    __syncthreads();
    // K1 B-frags -> registers (lane holds K1[32s+8g+jj][16n+cl])
    s8 K1B[2][4];
#pragma unroll
    for (int s = 0; s < 2; s++)
#pragma unroll
        for (int n = 0; n < 4; n++) {
            s8 v;
#pragma unroll
            for (int jj = 0; jj < 8; jj++)
                v[jj] = f2b(sK1[(32 * s + 8 * g + jj) * 64 + 16 * n + cl]);
            K1B[s][n] = v;
        }
    float b1v[4];
#pragma unroll
    for (int n = 0; n < 4; n++) b1v[n] = kb1[16 * n + cl];
    __syncthreads();
    // fragK2: A-frag layout of K2^T tiles: elem((n*2+s)*64+l)*8+jj = K2[32s+8*(l>>4)+jj][16n+(l&15)]
    for (int idx = tid; idx < 16384; idx += 256) {
        int n = idx >> 10, s = (idx >> 9) & 1, l2 = (idx >> 3) & 63, jj = idx & 7;
        fragK2[idx] = f2b(K2[(32 * s + 8 * (l2 >> 4) + jj) * 256 + 16 * n + (l2 & 15)]);
    }
    __syncthreads();

    const f4* K04 = (const f4*)sK0;
    const f4* KB04 = (const f4*)skb0;
    short* kh1w = kh1buf[w];
    float* msgw = msgbuf[w];
    const s8* K2f = (const s8*)fragK2;

    for (int bt = blockIdx.x; bt < EFF / 64; bt += gridDim.x) {
        const int ebase = bt * 64 + w * 16;
        const int te = ebase + cl;
        const int si = src[te];
        const int di = dst[te];
        const f4 xq = *(const f4*)(xf0 + (size_t)si * 16 + g * 4);
        const float* ep = ea + (size_t)te * 6;
        const float e0 = ep[0], e1 = ep[1], e2v = ep[2], e3 = ep[3], e4 = ep[4], e5 = ep[5];

        // ---- stage 1: kh0 = relu(ea @ K0 + kb0), built as A-frags ----
        s8 a1[2];
#pragma unroll
        for (int s = 0; s < 2; s++) {
            f4 accA = KB04[8 * s + 2 * g];
            f4 accB = KB04[8 * s + 2 * g + 1];
#pragma unroll
            for (int f = 0; f < 6; f++) {
                const float ef = (f == 0) ? e0 : (f == 1) ? e1 : (f == 2) ? e2v
                               : (f == 3) ? e3 : (f == 4) ? e4 : e5;
                accA += ef * K04[f * 16 + 8 * s + 2 * g];
                accB += ef * K04[f * 16 + 8 * s + 2 * g + 1];
            }
            s8 v;
#pragma unroll
            for (int jj = 0; jj < 4; jj++) v[jj] = f2b(fmaxf(accA[jj], 0.f));
#pragma unroll
            for (int jj = 0; jj < 4; jj++) v[4 + jj] = f2b(fmaxf(accB[jj], 0.f));
            a1[s] = v;
        }

        // ---- stage 2: kh1 = relu(kh0 @ K1 + b1) -> swizzled LDS ----
#pragma unroll
        for (int n = 0; n < 4; n++) {
            f4 c2 = {0.f, 0.f, 0.f, 0.f};
            c2 = __builtin_amdgcn_mfma_f32_16x16x32_bf16(a1[0], K1B[0][n], c2, 0, 0, 0);
            c2 = __builtin_amdgcn_mfma_f32_16x16x32_bf16(a1[1], K1B[1][n], c2, 0, 0, 0);
#pragma unroll
            for (int r = 0; r < 4; r++) {
                const int e = 4 * g + r;
                const int byteoff = (e * 128 + (16 * n + cl) * 2) ^ ((e & 7) << 4);
                *(short*)((char*)kh1w + byteoff) = f2b(fmaxf(c2[r] + b1v[n], 0.f));
            }
        }

        // ---- stage 3: ker tiles (transposed) + lane-local x contraction ----
        s8 a3[2];
#pragma unroll
        for (int s = 0; s < 2; s++) {
            const int byteoff = (cl * 128 + 64 * s + 16 * g) ^ ((cl & 7) << 4);
            a3[s] = *(const s8*)((const char*)kh1w + byteoff);
        }
        float p[16];
#pragma unroll
        for (int n = 0; n < 16; n++) {
            f4 acc = *(const f4*)(sb2 + 16 * n + 4 * g);   // b2 bias init
            acc = __builtin_amdgcn_mfma_f32_16x16x32_bf16(K2f[(2 * n + 0) * 64 + lane], a3[0], acc, 0, 0, 0);
            acc = __builtin_amdgcn_mfma_f32_16x16x32_bf16(K2f[(2 * n + 1) * 64 + lane], a3[1], acc, 0, 0, 0);
            float pv = acc[0] * xq[0] + acc[1] * xq[1] + acc[2] * xq[2] + acc[3] * xq[3];
            pv += __shfl_xor(pv, 16);
            pv += __shfl_xor(pv, 32);
            p[n] = pv;   // msg[e=cl, i=n], fully reduced in all 4 lane-groups
        }
        // each group writes its i-quarter; then per-edge coalesced atomic scatter
        f4 mv;
        if (g == 0)      mv = (f4){p[0], p[1], p[2], p[3]};
        else if (g == 1) mv = (f4){p[4], p[5], p[6], p[7]};
        else if (g == 2) mv = (f4){p[8], p[9], p[10], p[11]};
        else             mv = (f4){p[12], p[13], p[14], p[15]};
        *(f4*)(msgw + cl * 16 + g * 4) = mv;
        const f4 m4 = *(const f4*)(msgw + lane * 4);
        const int dd = dst[ebase + (lane >> 2)];
        float* ap = agg + (size_t)dd * 16 + (lane & 3) * 4;
        atomicAdd(ap + 0, m4[0]);
        atomicAdd(ap + 1, m4[1]);
        atomicAdd(ap + 2, m4[2]);
        atomicAdd(ap + 3, m4[3]);
        if (g == 0) atomicAdd(&deg[di], 1.0f);
    }
}

// ---- Phase F: combine + FiLM + flow decoder ----
__global__ void k_final(const float* __restrict__ root, const float* __restrict__ agg,
                        const float* __restrict__ num, const float* __restrict__ den,
                        const float* __restrict__ deg, const float* __restrict__ misc,
                        const float* __restrict__ dW, const float* __restrict__ db,
                        float* __restrict__ out) {
    __shared__ float ssc[16], ssh[16], sD[48], sdb[3];
    int tid = threadIdx.x;
    if (tid < 16) { ssc[tid] = misc[16 + tid]; ssh[tid] = misc[32 + tid]; }
    if (tid < 48) sD[tid] = dW[tid];
    if (tid < 3) sdb[tid] = db[tid];
    __syncthreads();
    int n = blockIdx.x * 256 + tid;
    if (n >= NF) return;
    float rdg = 1.0f / fmaxf(deg[n], 1.0f);
    float rdn = 1.0f / (den[n] + 1e-16f);
    float xo[16];
#pragma unroll
    for (int q = 0; q < 4; q++) {
        float4 r4 = reinterpret_cast<const float4*>(root)[n * 4 + q];
        float4 a4 = reinterpret_cast<const float4*>(agg)[n * 4 + q];
        float4 m4 = reinterpret_cast<const float4*>(num)[n * 4 + q];
        float v0 = r4.x + a4.x * rdg + m4.x * rdn;
        float v1 = r4.y + a4.y * rdg + m4.y * rdn;
        float v2 = r4.z + a4.z * rdg + m4.z * rdn;
        float v3 = r4.w + a4.w * rdg + m4.w * rdn;
        float r;
        r = fmaxf(v0, 0.f); xo[4 * q + 0] = r + (r * ssc[4 * q + 0] + ssh[4 * q + 0]);
        r = fmaxf(v1, 0.f); xo[4 * q + 1] = r + (r * ssc[4 * q + 1] + ssh[4 * q + 1]);
        r = fmaxf(v2, 0.f); xo[4 * q + 2] = r + (r * ssc[4 * q + 2] + ssh[4 * q + 2]);
        r = fmaxf(v3, 0.f); xo[4 * q + 3] = r + (r * ssc[4 * q + 3] + ssh[4 * q + 3]);
    }
#pragma unroll
    for (int k = 0; k < 3; k++) {
        float acc = sdb[k];
#pragma unroll
        for (int i = 0; i < 16; i++) acc += xo[i] * sD[i * 3 + k];
        out[n * 3 + k] = acc;
    }
}

extern "C" void kernel_launch(void* const* d_in, const int* in_sizes, int n_in,
                              void* d_out, int out_size, void* d_ws, size_t ws_size,
                              hipStream_t stream) {
    const float* flow_x   = (const float*)d_in[0];
    const float* memb_y   = (const float*)d_in[1];
    const float* tau      = (const float*)d_in[2];
    const float* ea_ff    = (const float*)d_in[3];
    const float* ea_mf    = (const float*)d_in[4];
    const float* enc_f_W  = (const float*)d_in[5];
    const float* enc_f_b  = (const float*)d_in[6];
    const float* enc_m_W1 = (const float*)d_in[7];
    const float* enc_m_b1 = (const float*)d_in[8];
    const float* enc_m_W2 = (const float*)d_in[9];
    const float* enc_m_b2 = (const float*)d_in[10];
    const float* K0       = (const float*)d_in[11];
    const float* kb0      = (const float*)d_in[12];
    const float* K1       = (const float*)d_in[13];
    const float* kb1      = (const float*)d_in[14];
    const float* K2       = (const float*)d_in[15];
    const float* kb2      = (const float*)d_in[16];
    const float* W_root   = (const float*)d_in[17];
    const float* b_root   = (const float*)d_in[18];
    const float* Wq       = (const float*)d_in[19];
    const float* Wk       = (const float*)d_in[20];
    const float* We       = (const float*)d_in[21];
    const float* Wv       = (const float*)d_in[22];
    const float* tc_W1    = (const float*)d_in[23];
    const float* tc_b1    = (const float*)d_in[24];
    const float* tc_W2    = (const float*)d_in[25];
    const float* tc_b2    = (const float*)d_in[26];
    const float* dec_f_W  = (const float*)d_in[27];
    const float* dec_f_b  = (const float*)d_in[28];
    const float* dec_m_W  = (const float*)d_in[29];
    const float* dec_m_b  = (const float*)d_in[30];
    const int* src_ff = (const int*)d_in[31];
    const int* dst_ff = (const int*)d_in[32];
    const int* src_mf = (const int*)d_in[33];
    const int* dst_mf = (const int*)d_in[34];

    float* out = (float*)d_out;
    float* ws = (float*)d_ws;
    float* misc = ws;                       // 64
    float* deg  = ws + 64;                  // NF   (zeroed)
    float* den  = deg + NF;                 // NF   (zeroed)
    unsigned* smax = (unsigned*)(den + NF); // NF   (zeroed; 0 < mono(any score))
    float* agg  = (float*)(smax + NF);      // NF*16 (zeroed)
    float* num  = agg + (size_t)NF * 16;    // NF*16 (zeroed)
    float* xm   = num + (size_t)NF * 16;    // NM*16
    float* xf0  = xm + (size_t)NM * 16;     // NF*16
    float* root = xf0 + (size_t)NF * 16;    // NF*16
    float* score = root + (size_t)NF * 16;  // EMF

    hipMemsetAsync(deg, 0, (size_t)NF * 35 * sizeof(float), stream);

    k_small<<<1, 64, 0, stream>>>(tau, tc_W1, tc_b1, tc_W2, tc_b2, misc);
    k_memb<<<(NM + 255) / 256, 256, 0, stream>>>(memb_y, enc_m_W1, enc_m_b1, enc_m_W2,
                                                 enc_m_b2, dec_m_W, dec_m_b, misc,
                                                 xm, out + (size_t)NF * 3);
    k_flow0<<<(NF + 255) / 256, 256, 0, stream>>>(flow_x, enc_f_W, enc_f_b, W_root, b_root,
                                                  misc, xf0, root);
    k_attn1<<<(EMF + 255) / 256, 256, 0, stream>>>(xf0, xm, ea_mf, src_mf, dst_mf,
                                                   Wq, Wk, We, score, smax);
    k_attn2<<<(EMF + 255) / 256, 256, 0, stream>>>(xm, src_mf, dst_mf, score, smax,
                                                   Wv, den, num);
    k_edge_mfma<<<2048, 256, 0, stream>>>(ea_ff, src_ff, dst_ff, K0, kb0,
                                          K1, kb1, K2, kb2, xf0, agg, deg);
    k_final<<<(NF + 255) / 256, 256, 0, stream>>>(root, agg, num, den, deg, misc,
                                                  dec_f_W, dec_f_b, out);
}

// Round 4
// 737.635 us; speedup vs baseline: 2.2405x; 1.1613x over previous
//
#include <hip/hip_runtime.h>
#include <hip/hip_bf16.h>
#include <math.h>

#define NF 50000
#define NM 5000
#define EFF 800000
#define EMF 200000

typedef __attribute__((ext_vector_type(8))) short s8;
typedef __attribute__((ext_vector_type(4))) float f4;

__device__ __forceinline__ unsigned mono(float f) {
    unsigned u = __float_as_uint(f);
    return (u & 0x80000000u) ? ~u : (u | 0x80000000u);
}
__device__ __forceinline__ float demono(unsigned m) {
    unsigned u = (m & 0x80000000u) ? (m & 0x7FFFFFFFu) : ~m;
    return __uint_as_float(u);
}
__device__ __forceinline__ short f2b(float f) {
    __hip_bfloat16 h = __float2bfloat16(f);
    return *reinterpret_cast<short*>(&h);
}

// ---- Phase A: timestep embedding + FiLM (tiny) ----
__global__ void k_small(const float* __restrict__ tau,
                        const float* __restrict__ tcW1, const float* __restrict__ tcb1,
                        const float* __restrict__ tcW2, const float* __restrict__ tcb2,
                        float* __restrict__ misc) {
    __shared__ float temb[16], h[16];
    int tid = threadIdx.x;
    float t = tau[0];
    if (tid < 8) {
        float fr = expf(-logf(10000.0f) * (float)tid / 8.0f);
        float a = t * fr;
        temb[tid] = sinf(a);
        temb[tid + 8] = cosf(a);
    }
    __syncthreads();
    if (tid < 16) {
        float acc = tcb1[tid];
#pragma unroll
        for (int i = 0; i < 16; i++) acc += temb[i] * tcW1[i * 16 + tid];
        h[tid] = fmaxf(acc, 0.f);
        misc[tid] = temb[tid];
    }
    __syncthreads();
    if (tid < 32) {
        float acc = tcb2[tid];
#pragma unroll
        for (int i = 0; i < 16; i++) acc += h[i] * tcW2[i * 32 + tid];
        misc[16 + tid] = acc;   // misc[16..31]=scale, misc[32..47]=shift
    }
}

// ---- Phase B: membrane encoder + decoder + knode/vnode precompute ----
__global__ void k_memb(const float* __restrict__ y,
                       const float* __restrict__ W1, const float* __restrict__ b1,
                       const float* __restrict__ W2, const float* __restrict__ b2,
                       const float* __restrict__ decW, const float* __restrict__ decb,
                       const float* __restrict__ Wk, const float* __restrict__ Wv,
                       const float* __restrict__ misc,
                       float* __restrict__ xm_out, float* __restrict__ knode,
                       float* __restrict__ vnode, float* __restrict__ outm) {
    __shared__ float sW1[304], sb1[16], sW2[256], sb2[16], sD[48], sdb[3], st[16];
    __shared__ float sWk[256], sWv[256];
    int tid = threadIdx.x;
    for (int i = tid; i < 304; i += 256) sW1[i] = W1[i];
    for (int i = tid; i < 256; i += 256) { sW2[i] = W2[i]; sWk[i] = Wk[i]; sWv[i] = Wv[i]; }
    if (tid < 16) { sb1[tid] = b1[tid]; sb2[tid] = b2[tid]; st[tid] = misc[tid]; }
    if (tid < 48) sD[tid] = decW[tid];
    if (tid < 3) sdb[tid] = decb[tid];
    __syncthreads();
    int n = blockIdx.x * 256 + tid;
    if (n >= NM) return;
    float i0 = y[n * 3], i1 = y[n * 3 + 1], i2 = y[n * 3 + 2];
    float h1[16];
#pragma unroll
    for (int c = 0; c < 16; c++) {
        float acc = sb1[c] + i0 * sW1[c] + i1 * sW1[16 + c] + i2 * sW1[32 + c];
#pragma unroll
        for (int i = 0; i < 16; i++) acc += st[i] * sW1[(3 + i) * 16 + c];
        h1[c] = fmaxf(acc, 0.f);
    }
    float xm[16];
#pragma unroll
    for (int c = 0; c < 16; c++) {
        float acc = sb2[c];
#pragma unroll
        for (int i = 0; i < 16; i++) acc += h1[i] * sW2[i * 16 + c];
        xm[c] = fmaxf(acc, 0.f);
    }
#pragma unroll
    for (int q = 0; q < 4; q++) {
        float4 v = make_float4(xm[4 * q], xm[4 * q + 1], xm[4 * q + 2], xm[4 * q + 3]);
        reinterpret_cast<float4*>(xm_out)[n * 4 + q] = v;
    }
    float kn[16], vn[16];
#pragma unroll
    for (int c = 0; c < 16; c++) {
        float ak = 0.f, av = 0.f;
#pragma unroll
        for (int i = 0; i < 16; i++) { ak += xm[i] * sWk[i * 16 + c]; av += xm[i] * sWv[i * 16 + c]; }
        kn[c] = ak; vn[c] = av;
    }
#pragma unroll
    for (int q = 0; q < 4; q++) {
        reinterpret_cast<float4*>(knode)[n * 4 + q] =
            make_float4(kn[4 * q], kn[4 * q + 1], kn[4 * q + 2], kn[4 * q + 3]);
        reinterpret_cast<float4*>(vnode)[n * 4 + q] =
            make_float4(vn[4 * q], vn[4 * q + 1], vn[4 * q + 2], vn[4 * q + 3]);
    }
#pragma unroll
    for (int k = 0; k < 3; k++) {
        float acc = sdb[k];
#pragma unroll
        for (int i = 0; i < 16; i++) acc += xm[i] * sD[i * 3 + k];
        outm[n * 3 + k] = acc;
    }
}

// ---- Phase C: flow encoder + qnode precompute ----
__global__ void k_flow0(const float* __restrict__ x,
                        const float* __restrict__ W, const float* __restrict__ b,
                        const float* __restrict__ Wq,
                        const float* __restrict__ misc,
                        float* __restrict__ xf0, float* __restrict__ qnode) {
    __shared__ float sW[304], sb[16], st[16], sWq[256];
    int tid = threadIdx.x;
    for (int i = tid; i < 304; i += 256) sW[i] = W[i];
    for (int i = tid; i < 256; i += 256) sWq[i] = Wq[i];
    if (tid < 16) { sb[tid] = b[tid]; st[tid] = misc[tid]; }
    __syncthreads();
    int n = blockIdx.x * 256 + tid;
    if (n >= NF) return;
    float i0 = x[n * 3], i1 = x[n * 3 + 1], i2 = x[n * 3 + 2];
    float f[16];
#pragma unroll
    for (int c = 0; c < 16; c++) {
        float acc = sb[c] + i0 * sW[c] + i1 * sW[16 + c] + i2 * sW[32 + c];
#pragma unroll
        for (int i = 0; i < 16; i++) acc += st[i] * sW[(3 + i) * 16 + c];
        f[c] = acc;
    }
#pragma unroll
    for (int q = 0; q < 4; q++)
        reinterpret_cast<float4*>(xf0)[n * 4 + q] =
            make_float4(f[4 * q], f[4 * q + 1], f[4 * q + 2], f[4 * q + 3]);
    float qv[16];
#pragma unroll
    for (int c = 0; c < 16; c++) {
        float aq = 0.f;
#pragma unroll
        for (int i = 0; i < 16; i++) aq += f[i] * sWq[i * 16 + c];
        qv[c] = aq;
    }
#pragma unroll
    for (int q = 0; q < 4; q++)
        reinterpret_cast<float4*>(qnode)[n * 4 + q] =
            make_float4(qv[4 * q], qv[4 * q + 1], qv[4 * q + 2], qv[4 * q + 3]);
}

__device__ __forceinline__ float attn_score(const float* __restrict__ qnode,
                                            const float* __restrict__ knode,
                                            const float* __restrict__ se,
                                            const float* __restrict__ ea,
                                            int s, int d, int t) {
    const float2* ep = reinterpret_cast<const float2*>(ea + (size_t)t * 6);
    float2 e01 = ep[0], e23 = ep[1], e45 = ep[2];
    float sc = 0.f;
#pragma unroll
    for (int q = 0; q < 4; q++) {
        float4 q4 = reinterpret_cast<const float4*>(qnode)[(size_t)d * 4 + q];
        float4 k4 = reinterpret_cast<const float4*>(knode)[(size_t)s * 4 + q];
        float kj[4];
#pragma unroll
        for (int j = 0; j < 4; j++) {
            int c = 4 * q + j;
            kj[j] = e01.x * se[c] + e01.y * se[16 + c] + e23.x * se[32 + c]
                  + e23.y * se[48 + c] + e45.x * se[64 + c] + e45.y * se[80 + c];
        }
        sc += q4.x * (k4.x + kj[0]) + q4.y * (k4.y + kj[1])
            + q4.z * (k4.z + kj[2]) + q4.w * (k4.w + kj[3]);
    }
    return sc * 0.25f;
}

// ---- Phase D1: attention segment-max ----
__global__ void k_attn1(const float* __restrict__ qnode, const float* __restrict__ knode,
                        const float* __restrict__ ea,
                        const int* __restrict__ src, const int* __restrict__ dst,
                        const float* __restrict__ We, unsigned* __restrict__ smax) {
    __shared__ float se[96];
    int tid = threadIdx.x;
    if (tid < 96) se[tid] = We[tid];
    __syncthreads();
    int t = blockIdx.x * 256 + tid;
    if (t >= EMF) return;
    int s = src[t], d = dst[t];
    float sc = attn_score(qnode, knode, se, ea, s, d, t);
    atomicMax(&smax[d], mono(sc));
}

// ---- Phase D2: recompute score, exp(sc - max), scatter to partials ----
__global__ void k_attn2(const float* __restrict__ qnode, const float* __restrict__ knode,
                        const float* __restrict__ vnode, const float* __restrict__ ea,
                        const int* __restrict__ src, const int* __restrict__ dst,
                        const float* __restrict__ We, const unsigned* __restrict__ smax,
                        float* __restrict__ denP, float* __restrict__ numP, int NPm1) {
    __shared__ float se[96];
    int tid = threadIdx.x;
    if (tid < 96) se[tid] = We[tid];
    __syncthreads();
    int t = blockIdx.x * 256 + tid;
    if (t >= EMF) return;
    int s = src[t], d = dst[t];
    float sc = attn_score(qnode, knode, se, ea, s, d, t);
    float e = expf(sc - demono(smax[d]));
    int bp = blockIdx.x & NPm1;
    atomicAdd(&denP[(size_t)bp * NF + d], e);
    float* nrow = numP + ((size_t)bp * NF + (size_t)d) * 16;
#pragma unroll
    for (int q = 0; q < 4; q++) {
        float4 v4 = reinterpret_cast<const float4*>(vnode)[(size_t)s * 4 + q];
        atomicAdd(nrow + 4 * q + 0, e * v4.x);
        atomicAdd(nrow + 4 * q + 1, e * v4.y);
        atomicAdd(nrow + 4 * q + 2, e * v4.z);
        atomicAdd(nrow + 4 * q + 3, e * v4.w);
    }
}

// ---- Phase E: fused NNConv edge kernel, MFMA + XCD-partial scatter ----
__global__ void __launch_bounds__(256, 2) k_edge_mfma(
        const float* __restrict__ ea, const int* __restrict__ src, const int* __restrict__ dst,
        const float* __restrict__ K0, const float* __restrict__ kb0,
        const float* __restrict__ K1, const float* __restrict__ kb1,
        const float* __restrict__ K2, const float* __restrict__ kb2,
        const float* __restrict__ xf0,
        float* __restrict__ aggP, float* __restrict__ degP, int NPm1) {
    __shared__ __align__(16) char smem_big[32768];   // sK1 fp32 (16KB) then fragK2 bf16 (32KB)
    __shared__ __align__(16) float sK0[384];
    __shared__ __align__(16) float skb0[64];
    __shared__ __align__(16) float sb2[256];
    __shared__ __align__(16) short kh1buf[4][1024];  // per-wave [16 e][64 c] bf16, swizzled
    __shared__ __align__(16) float msgbuf[4][256];   // per-wave [16 e][16 i]

    const int tid = threadIdx.x;
    const int w = tid >> 6, lane = tid & 63;
    const int cl = lane & 15, g = lane >> 4;

    float* sK1 = (float*)smem_big;
    short* fragK2 = (short*)smem_big;
    for (int i = tid; i < 4096; i += 256) sK1[i] = K1[i];
    for (int i = tid; i < 384; i += 256) sK0[i] = K0[i];
    if (tid < 64) skb0[tid] = kb0[tid];
    if (tid < 256) sb2[tid] = kb2[tid];
    __syncthreads();
    // K1 B-frags -> registers (lane holds K1[32s+8g+jj][16n+cl])
    s8 K1B[2][4];
#pragma unroll
    for (int s = 0; s < 2; s++)
#pragma unroll
        for (int n = 0; n < 4; n++) {
            s8 v;
#pragma unroll
            for (int jj = 0; jj < 8; jj++)
                v[jj] = f2b(sK1[(32 * s + 8 * g + jj) * 64 + 16 * n + cl]);
            K1B[s][n] = v;
        }
    float b1v[4];
#pragma unroll
    for (int n = 0; n < 4; n++) b1v[n] = kb1[16 * n + cl];
    __syncthreads();
    // fragK2: A-frag layout of K2^T tiles
    for (int idx = tid; idx < 16384; idx += 256) {
        int n = idx >> 10, s = (idx >> 9) & 1, l2 = (idx >> 3) & 63, jj = idx & 7;
        fragK2[idx] = f2b(K2[(32 * s + 8 * (l2 >> 4) + jj) * 256 + 16 * n + (l2 & 15)]);
    }
    __syncthreads();

    const f4* K04 = (const f4*)sK0;
    const f4* KB04 = (const f4*)skb0;
    short* kh1w = kh1buf[w];
    float* msgw = msgbuf[w];
    const s8* K2f = (const s8*)fragK2;

    const int bp = blockIdx.x & NPm1;
    float* aggw = aggP + (size_t)bp * NF * 16;
    float* degw = degP + (size_t)bp * NF;

    for (int bt = blockIdx.x; bt < EFF / 64; bt += gridDim.x) {
        const int ebase = bt * 64 + w * 16;
        const int te = ebase + cl;
        const int si = src[te];
        const int di = dst[te];
        const f4 xq = *(const f4*)(xf0 + (size_t)si * 16 + g * 4);
        const float2* ep2 = reinterpret_cast<const float2*>(ea + (size_t)te * 6);
        const float2 p01 = ep2[0], p23 = ep2[1], p45 = ep2[2];
        const float e0 = p01.x, e1 = p01.y, e2v = p23.x, e3 = p23.y, e4 = p45.x, e5 = p45.y;

        // ---- stage 1: kh0 = relu(ea @ K0 + kb0), built as A-frags ----
        s8 a1[2];
#pragma unroll
        for (int s = 0; s < 2; s++) {
            f4 accA = KB04[8 * s + 2 * g];
            f4 accB = KB04[8 * s + 2 * g + 1];
#pragma unroll
            for (int f = 0; f < 6; f++) {
                const float ef = (f == 0) ? e0 : (f == 1) ? e1 : (f == 2) ? e2v
                               : (f == 3) ? e3 : (f == 4) ? e4 : e5;
                accA += ef * K04[f * 16 + 8 * s + 2 * g];
                accB += ef * K04[f * 16 + 8 * s + 2 * g + 1];
            }
            s8 v;
#pragma unroll
            for (int jj = 0; jj < 4; jj++) v[jj] = f2b(fmaxf(accA[jj], 0.f));
#pragma unroll
            for (int jj = 0; jj < 4; jj++) v[4 + jj] = f2b(fmaxf(accB[jj], 0.f));
            a1[s] = v;
        }

        // ---- stage 2: kh1 = relu(kh0 @ K1 + b1) -> swizzled LDS ----
#pragma unroll
        for (int n = 0; n < 4; n++) {
            f4 c2 = {0.f, 0.f, 0.f, 0.f};
            c2 = __builtin_amdgcn_mfma_f32_16x16x32_bf16(a1[0], K1B[0][n], c2, 0, 0, 0);
            c2 = __builtin_amdgcn_mfma_f32_16x16x32_bf16(a1[1], K1B[1][n], c2, 0, 0, 0);
#pragma unroll
            for (int r = 0; r < 4; r++) {
                const int e = 4 * g + r;
                const int byteoff = (e * 128 + (16 * n + cl) * 2) ^ ((e & 7) << 4);
                *(short*)((char*)kh1w + byteoff) = f2b(fmaxf(c2[r] + b1v[n], 0.f));
            }
        }

        // ---- stage 3: ker tiles (transposed) + lane-local x contraction ----
        s8 a3[2];
#pragma unroll
        for (int s = 0; s < 2; s++) {
            const int byteoff = (cl * 128 + 64 * s + 16 * g) ^ ((cl & 7) << 4);
            a3[s] = *(const s8*)((const char*)kh1w + byteoff);
        }
        float p[16];
#pragma unroll
        for (int n = 0; n < 16; n++) {
            f4 acc = *(const f4*)(sb2 + 16 * n + 4 * g);   // b2 bias init
            acc = __builtin_amdgcn_mfma_f32_16x16x32_bf16(K2f[(2 * n + 0) * 64 + lane], a3[0], acc, 0, 0, 0);
            acc = __builtin_amdgcn_mfma_f32_16x16x32_bf16(K2f[(2 * n + 1) * 64 + lane], a3[1], acc, 0, 0, 0);
            float pv = acc[0] * xq[0] + acc[1] * xq[1] + acc[2] * xq[2] + acc[3] * xq[3];
            pv += __shfl_xor(pv, 16);
            pv += __shfl_xor(pv, 32);
            p[n] = pv;
        }
        f4 mv;
        if (g == 0)      mv = (f4){p[0], p[1], p[2], p[3]};
        else if (g == 1) mv = (f4){p[4], p[5], p[6], p[7]};
        else if (g == 2) mv = (f4){p[8], p[9], p[10], p[11]};
        else             mv = (f4){p[12], p[13], p[14], p[15]};
        *(f4*)(msgw + cl * 16 + g * 4) = mv;
        const f4 m4 = *(const f4*)(msgw + lane * 4);
        const int dd = dst[ebase + (lane >> 2)];
        float* ap = aggw + (size_t)dd * 16 + (lane & 3) * 4;
        atomicAdd(ap + 0, m4[0]);
        atomicAdd(ap + 1, m4[1]);
        atomicAdd(ap + 2, m4[2]);
        atomicAdd(ap + 3, m4[3]);
        if (g == 0) atomicAdd(&degw[di], 1.0f);
    }
}

// ---- Phase F: combine partials + root recompute + FiLM + flow decoder ----
__global__ void k_final(const float* __restrict__ xf0, const float* __restrict__ aggP,
                        const float* __restrict__ numP, const float* __restrict__ denP,
                        const float* __restrict__ degP, const float* __restrict__ misc,
                        const float* __restrict__ Wr, const float* __restrict__ br,
                        const float* __restrict__ dW, const float* __restrict__ db,
                        float* __restrict__ out, int NP) {
    __shared__ float ssc[16], ssh[16], sD[48], sdb[3], sWr[256], sbr[16];
    int tid = threadIdx.x;
    if (tid < 16) { ssc[tid] = misc[16 + tid]; ssh[tid] = misc[32 + tid]; sbr[tid] = br[tid]; }
    if (tid < 48) sD[tid] = dW[tid];
    if (tid < 3) sdb[tid] = db[tid];
    for (int i = tid; i < 256; i += 256) sWr[i] = Wr[i];
    __syncthreads();
    int n = blockIdx.x * 256 + tid;
    if (n >= NF) return;
    float f[16];
#pragma unroll
    for (int q = 0; q < 4; q++) {
        float4 v = reinterpret_cast<const float4*>(xf0)[n * 4 + q];
        f[4 * q] = v.x; f[4 * q + 1] = v.y; f[4 * q + 2] = v.z; f[4 * q + 3] = v.w;
    }
    float agg[16], num[16], den = 0.f, dg = 0.f;
#pragma unroll
    for (int i = 0; i < 16; i++) { agg[i] = 0.f; num[i] = 0.f; }
    for (int p = 0; p < NP; p++) {
        const f4* ap = (const f4*)(aggP + ((size_t)p * NF + n) * 16);
        const f4* mp = (const f4*)(numP + ((size_t)p * NF + n) * 16);
#pragma unroll
        for (int q = 0; q < 4; q++) {
            f4 a4 = ap[q], m4 = mp[q];
#pragma unroll
            for (int j = 0; j < 4; j++) { agg[4 * q + j] += a4[j]; num[4 * q + j] += m4[j]; }
        }
        den += denP[(size_t)p * NF + n];
        dg  += degP[(size_t)p * NF + n];
    }
    float rdg = 1.0f / fmaxf(dg, 1.0f);
    float rdn = 1.0f / (den + 1e-16f);
    float xo[16];
#pragma unroll
    for (int c = 0; c < 16; c++) {
        float ar = sbr[c];
#pragma unroll
        for (int i = 0; i < 16; i++) ar += f[i] * sWr[i * 16 + c];   // root, round-2 order
        float v = ar + agg[c] * rdg + num[c] * rdn;
        float rr = fmaxf(v, 0.f);
        xo[c] = rr + (rr * ssc[c] + ssh[c]);
    }
#pragma unroll
    for (int k = 0; k < 3; k++) {
        float acc = sdb[k];
#pragma unroll
        for (int i = 0; i < 16; i++) acc += xo[i] * sD[i * 3 + k];
        out[n * 3 + k] = acc;
    }
}

extern "C" void kernel_launch(void* const* d_in, const int* in_sizes, int n_in,
                              void* d_out, int out_size, void* d_ws, size_t ws_size,
                              hipStream_t stream) {
    const float* flow_x   = (const float*)d_in[0];
    const float* memb_y   = (const float*)d_in[1];
    const float* tau      = (const float*)d_in[2];
    const float* ea_ff    = (const float*)d_in[3];
    const float* ea_mf    = (const float*)d_in[4];
    const float* enc_f_W  = (const float*)d_in[5];
    const float* enc_f_b  = (const float*)d_in[6];
    const float* enc_m_W1 = (const float*)d_in[7];
    const float* enc_m_b1 = (const float*)d_in[8];
    const float* enc_m_W2 = (const float*)d_in[9];
    const float* enc_m_b2 = (const float*)d_in[10];
    const float* K0       = (const float*)d_in[11];
    const float* kb0      = (const float*)d_in[12];
    const float* K1       = (const float*)d_in[13];
    const float* kb1      = (const float*)d_in[14];
    const float* K2       = (const float*)d_in[15];
    const float* kb2      = (const float*)d_in[16];
    const float* W_root   = (const float*)d_in[17];
    const float* b_root   = (const float*)d_in[18];
    const float* Wq       = (const float*)d_in[19];
    const float* Wk       = (const float*)d_in[20];
    const float* We       = (const float*)d_in[21];
    const float* Wv       = (const float*)d_in[22];
    const float* tc_W1    = (const float*)d_in[23];
    const float* tc_b1    = (const float*)d_in[24];
    const float* tc_W2    = (const float*)d_in[25];
    const float* tc_b2    = (const float*)d_in[26];
    const float* dec_f_W  = (const float*)d_in[27];
    const float* dec_f_b  = (const float*)d_in[28];
    const float* dec_m_W  = (const float*)d_in[29];
    const float* dec_m_b  = (const float*)d_in[30];
    const int* src_ff = (const int*)d_in[31];
    const int* dst_ff = (const int*)d_in[32];
    const int* src_mf = (const int*)d_in[33];
    const int* dst_mf = (const int*)d_in[34];

    float* out = (float*)d_out;
    float* ws = (float*)d_ws;

    // fixed region (floats): 64 + NM*48 + NF*32 = 1,840,064 fl = 7.36 MB
    float* misc  = ws;                          // 64
    float* xm    = ws + 64;                     // NM*16
    float* knode = xm + (size_t)NM * 16;        // NM*16
    float* vnode = knode + (size_t)NM * 16;     // NM*16
    float* xf0   = vnode + (size_t)NM * 16;     // NF*16
    float* qnode = xf0 + (size_t)NF * 16;       // NF*16
    float* zbase = qnode + (size_t)NF * 16;     // zeroed region starts here
    size_t fixed = (size_t)(zbase - ws);

    // NP partial copies of (agg 16, num 16, den 1, deg 1) = NF*34 each.
    // NP=1 total = 14.36 MB (proven to fit: round 2 used 14.52 MB).
    int NP = 8;
    while (NP > 1 && (fixed + (size_t)NF + (size_t)NP * NF * 34) * sizeof(float) > ws_size)
        NP >>= 1;
    unsigned* smax = (unsigned*)zbase;           // NF (zeroed; 0 < mono(any finite))
    float* aggP = zbase + NF;                    // NP*NF*16
    float* numP = aggP + (size_t)NP * NF * 16;   // NP*NF*16
    float* denP = numP + (size_t)NP * NF * 16;   // NP*NF
    float* degP = denP + (size_t)NP * NF;        // NP*NF

    hipMemsetAsync(zbase, 0, (size_t)NF * (1 + 34 * (size_t)NP) * sizeof(float), stream);

    k_small<<<1, 64, 0, stream>>>(tau, tc_W1, tc_b1, tc_W2, tc_b2, misc);
    k_memb<<<(NM + 255) / 256, 256, 0, stream>>>(memb_y, enc_m_W1, enc_m_b1, enc_m_W2,
                                                 enc_m_b2, dec_m_W, dec_m_b, Wk, Wv, misc,
                                                 xm, knode, vnode, out + (size_t)NF * 3);
    k_flow0<<<(NF + 255) / 256, 256, 0, stream>>>(flow_x, enc_f_W, enc_f_b, Wq, misc,
                                                  xf0, qnode);
    k_attn1<<<(EMF + 255) / 256, 256, 0, stream>>>(qnode, knode, ea_mf, src_mf, dst_mf,
                                                   We, smax);
    k_attn2<<<(EMF + 255) / 256, 256, 0, stream>>>(qnode, knode, vnode, ea_mf, src_mf, dst_mf,
                                                   We, smax, denP, numP, NP - 1);
    k_edge_mfma<<<2048, 256, 0, stream>>>(ea_ff, src_ff, dst_ff, K0, kb0,
                                          K1, kb1, K2, kb2, xf0, aggP, degP, NP - 1);
    k_final<<<(NF + 255) / 256, 256, 0, stream>>>(xf0, aggP, numP, denP, degP, misc,
                                                  W_root, b_root, dec_f_W, dec_f_b, out, NP);
}